// Round 3
// baseline (3101.614 us; speedup 1.0000x reference)
//
#include <hip/hip_runtime.h>

#define N_ROWS 4096
#define D_DIM  2048
#define V_DIM  32000

typedef unsigned char  u8;
typedef unsigned short u16;
typedef __attribute__((ext_vector_type(4))) int   i32x4;
typedef __attribute__((ext_vector_type(8))) int   i32x8;
typedef __attribute__((ext_vector_type(4))) float f32x4;

__device__ __forceinline__ unsigned pack4_fp8(float a, float b, float c, float d) {
    unsigned w = __builtin_amdgcn_cvt_pk_fp8_f32(a, b, 0, false);   // bytes 0,1
    w = __builtin_amdgcn_cvt_pk_fp8_f32(c, d, w, true);             // bytes 2,3
    return w;
}
__device__ __forceinline__ u8 f2fp8(float a) {
    return (u8)(__builtin_amdgcn_cvt_pk_fp8_f32(a, a, 0, false) & 0xFF);
}

// ---- zero the per-row accumulators (ws is poisoned 0xAA before every call) ----
__global__ void init_acc(float* __restrict__ p, int n) {
    int i = blockIdx.x * blockDim.x + threadIdx.x;
    if (i < n) p[i] = 0.0f;
}

// ---- convert input A fp32 [N,D] -> fp8 e4m3 [N,D] ----
__global__ void convert_a_fp8(const float4* __restrict__ in, uint4* __restrict__ out, int n16) {
    int i = blockIdx.x * blockDim.x + threadIdx.x;
    int stride = gridDim.x * blockDim.x;
    for (; i < n16; i += stride) {
        float4 v0 = in[i * 4 + 0], v1 = in[i * 4 + 1];
        float4 v2 = in[i * 4 + 2], v3 = in[i * 4 + 3];
        uint4 o;
        o.x = pack4_fp8(v0.x, v0.y, v0.z, v0.w);
        o.y = pack4_fp8(v1.x, v1.y, v1.z, v1.w);
        o.z = pack4_fp8(v2.x, v2.y, v2.z, v2.w);
        o.w = pack4_fp8(v3.x, v3.y, v3.z, v3.w);
        out[i] = o;
    }
}

// ---- transpose-convert weight fp32 [D,V] -> fp8 Wt [V,D] ----
// 64x64 tile; chunk-swizzled LDS (slot = (d>>4) ^ ((v>>2)&3)) for conflict-light phases.
__global__ __launch_bounds__(256) void transpose_w_fp8(const float* __restrict__ W,
                                                       u8* __restrict__ Wt) {
    __shared__ u8 tile[64 * 64];
    const int v0 = blockIdx.x * 64;
    const int d0 = blockIdx.y * 64;
    const int tid = threadIdx.x;

    const int vch = (tid & 15) * 4;          // 4 consecutive v per thread
    const int dr0 = tid >> 4;                // 0..15
#pragma unroll
    for (int i = 0; i < 4; ++i) {
        int d = dr0 + i * 16;                // 0..63
        float4 w = *(const float4*)&W[(size_t)(d0 + d) * V_DIM + v0 + vch];
        float wv[4] = {w.x, w.y, w.z, w.w};
#pragma unroll
        for (int j = 0; j < 4; ++j) {
            int v = vch + j;
            int slot = (d >> 4) ^ ((v >> 2) & 3);
            tile[v * 64 + slot * 16 + (d & 15)] = f2fp8(wv[j]);
        }
    }
    __syncthreads();

    // store: thread t -> row v = t>>2, slot s = t&3 holds global d-chunk c = s ^ ((v>>2)&3)
    const int v = tid >> 2, s = tid & 3;
    const int c = s ^ ((v >> 2) & 3);
    uint4 val = *(const uint4*)&tile[tid * 16];
    *(uint4*)&Wt[(size_t)(v0 + v) * D_DIM + d0 + c * 16] = val;
}

// ---- fused fp8 GEMM (MX-scaled MFMA, unit scales) + softcap + partial CE reductions ----
// C-tile 128x128, BK=128 (one 16x16x128 MFMA K-step per iter), 4 waves 2x2,
// each wave 4x4 MFMAs. LDS rows are 128 B = 8 chunks of 16 B; chunk g of row r
// stored at slot g ^ (r&7) (all-bank spread, 2-way = free).
__global__ __launch_bounds__(256) void gemm_ce(
    const u8* __restrict__ A, const u8* __restrict__ Wt,
    const int* __restrict__ targets,
    float* __restrict__ sumexp, float* __restrict__ sumlog, float* __restrict__ tlogit)
{
    __shared__ u8 lsA[128 * 128];
    __shared__ u8 lsB[128 * 128];

    const int tid   = threadIdx.x;
    const int lane  = tid & 63;
    const int wave  = tid >> 6;
    const int wr    = wave >> 1, wc = wave & 1;
    const int col16 = lane & 15, quad = lane >> 4;

    const int rowbase = blockIdx.x * 128;
    const int colbase = blockIdx.y * 128;

    f32x4 acc[4][4];
#pragma unroll
    for (int i = 0; i < 4; ++i)
#pragma unroll
        for (int j = 0; j < 4; ++j)
            acc[i][j] = (f32x4){0.f, 0.f, 0.f, 0.f};

    // staging: 4 chunks per matrix per thread; chunk c -> LDS bytes [c*16, c*16+16)
    // holds global k-chunk g = (c&7) ^ (r&7), r = c>>3
    const u8* gA[4]; const u8* gB[4];
    u8* lA[4]; u8* lB[4];
#pragma unroll
    for (int i = 0; i < 4; ++i) {
        int c = tid + 256 * i;
        int r = c >> 3;
        int g = (c & 7) ^ (r & 7);
        gA[i] = A  + (size_t)(rowbase + r) * D_DIM + g * 16;
        gB[i] = Wt + (size_t)(colbase + r) * D_DIM + g * 16;
        lA[i] = &lsA[c * 16];
        lB[i] = &lsB[c * 16];
    }

    // frag-read offsets: row r, k-bytes [quad*32, quad*32+32) = g-chunks {2q, 2q+1}
    int aoff[4][2], boff[4][2];
#pragma unroll
    for (int mi = 0; mi < 4; ++mi) {
        int ra = wr * 64 + mi * 16 + col16;
        int rb = wc * 64 + mi * 16 + col16;
        aoff[mi][0] = ra * 128 + ((2 * quad)     ^ (ra & 7)) * 16;
        aoff[mi][1] = ra * 128 + ((2 * quad + 1) ^ (ra & 7)) * 16;
        boff[mi][0] = rb * 128 + ((2 * quad)     ^ (rb & 7)) * 16;
        boff[mi][1] = rb * 128 + ((2 * quad + 1) ^ (rb & 7)) * 16;
    }

    for (int kt = 0; kt < D_DIM / 128; ++kt) {
        const int ko = kt * 128;
#pragma unroll
        for (int i = 0; i < 4; ++i) {
            __builtin_amdgcn_global_load_lds(
                (const __attribute__((address_space(1))) void*)(gA[i] + ko),
                (__attribute__((address_space(3))) void*)lA[i], 16, 0, 0);
            __builtin_amdgcn_global_load_lds(
                (const __attribute__((address_space(1))) void*)(gB[i] + ko),
                (__attribute__((address_space(3))) void*)lB[i], 16, 0, 0);
        }
        __syncthreads();

        i32x8 af[4], bfr[4];
#pragma unroll
        for (int mi = 0; mi < 4; ++mi) {
            i32x4 lo = *(const i32x4*)&lsA[aoff[mi][0]];
            i32x4 hi = *(const i32x4*)&lsA[aoff[mi][1]];
            af[mi] = __builtin_shufflevector(lo, hi, 0, 1, 2, 3, 4, 5, 6, 7);
        }
#pragma unroll
        for (int ni = 0; ni < 4; ++ni) {
            i32x4 lo = *(const i32x4*)&lsB[boff[ni][0]];
            i32x4 hi = *(const i32x4*)&lsB[boff[ni][1]];
            bfr[ni] = __builtin_shufflevector(lo, hi, 0, 1, 2, 3, 4, 5, 6, 7);
        }

#pragma unroll
        for (int mi = 0; mi < 4; ++mi)
#pragma unroll
            for (int ni = 0; ni < 4; ++ni)
                acc[mi][ni] = __builtin_amdgcn_mfma_scale_f32_16x16x128_f8f6f4(
                    af[mi], bfr[ni], acc[mi][ni],
                    0 /*cbsz: fp8 e4m3*/, 0 /*blgp: fp8 e4m3*/,
                    0, 0x7F7F7F7F,    // scale_a opsel, e8m0 = 127 -> 1.0
                    0, 0x7F7F7F7F);   // scale_b
        __syncthreads();
    }

    // ---- epilogue: C/D layout col=lane&15, row=quad*4+reg (shape-determined, m121-128) ----
#pragma unroll
    for (int mi = 0; mi < 4; ++mi) {
        int grows[4], tgts[4];
#pragma unroll
        for (int r = 0; r < 4; ++r) {
            grows[r] = rowbase + wr * 64 + mi * 16 + quad * 4 + r;
            tgts[r]  = targets[grows[r]];
        }
        float se[4] = {0.f, 0.f, 0.f, 0.f};
        float sl[4] = {0.f, 0.f, 0.f, 0.f};
#pragma unroll
        for (int ni = 0; ni < 4; ++ni) {
            int gcol = colbase + wc * 64 + ni * 16 + col16;
            f32x4 v = acc[mi][ni];
#pragma unroll
            for (int r = 0; r < 4; ++r) {
                float a  = v[r];
                float e2 = __expf(a * (2.0f / 30.0f));     // exp(2*a/30)
                float th = 1.0f - 2.0f / (e2 + 1.0f);      // tanh(a/30)
                float l  = 30.0f * th;
                float el = __expf(l);
                se[r] += el;
                sl[r] += l;
                if (tgts[r] == gcol) tlogit[grows[r]] = l; // unique writer
            }
        }
#pragma unroll
        for (int r = 0; r < 4; ++r) {
            float e = se[r], s = sl[r];
#pragma unroll
            for (int off = 1; off < 16; off <<= 1) {
                e += __shfl_xor(e, off);
                s += __shfl_xor(s, off);
            }
            if (col16 == 0) {
                atomicAdd(&sumexp[grows[r]], e);
                atomicAdd(&sumlog[grows[r]], s);
            }
        }
    }
}

// ---- final scalar reduction ----
__global__ void finalize(const float* __restrict__ sumexp, const float* __restrict__ sumlog,
                         const float* __restrict__ tlogit, const int* __restrict__ targets,
                         float* __restrict__ out)
{
    const int tid = threadIdx.x;
    float acc = 0.f, cnt = 0.f;
    for (int r = tid; r < N_ROWS; r += 256) {
        int tg = targets[r];
        if (tg != -100) {
            float lse    = __logf(sumexp[r]);
            float nll    = lse - tlogit[r];
            float smooth = lse - sumlog[r] * (1.0f / V_DIM);
            float ce     = 0.9f * nll + 0.1f * smooth;
            float z      = 1e-4f * lse * lse;
            acc += ce + z;
            cnt += 1.f;
        }
    }
#pragma unroll
    for (int off = 1; off < 64; off <<= 1) {
        acc += __shfl_xor(acc, off);
        cnt += __shfl_xor(cnt, off);
    }
    __shared__ float sa[4], sc[4];
    if ((tid & 63) == 0) { sa[tid >> 6] = acc; sc[tid >> 6] = cnt; }
    __syncthreads();
    if (tid == 0) {
        float t = sa[0] + sa[1] + sa[2] + sa[3];
        float c = sc[0] + sc[1] + sc[2] + sc[3];
        out[0] = t / c;
    }
}

extern "C" void kernel_launch(void* const* d_in, const int* in_sizes, int n_in,
                              void* d_out, int out_size, void* d_ws, size_t ws_size,
                              hipStream_t stream) {
    const float* A  = (const float*)d_in[0];   // [4096, 2048]
    const float* W  = (const float*)d_in[1];   // [2048, 32000]
    const int*   tg = (const int*)d_in[2];     // [4096]
    // d_in[3] = bias scalar 0 (falsy) -> ignored
    float* out = (float*)d_out;

    char* ws = (char*)d_ws;
    u8* A8 = (u8*)ws;
    size_t off = (size_t)N_ROWS * D_DIM;                    // 8 MB
    u8* Wt8 = (u8*)(ws + off);
    off += (size_t)V_DIM * D_DIM;                           // 64 MB
    float* sumexp = (float*)(ws + off); off += (size_t)N_ROWS * sizeof(float);
    float* sumlog = (float*)(ws + off); off += (size_t)N_ROWS * sizeof(float);
    float* tlog   = (float*)(ws + off); off += (size_t)N_ROWS * sizeof(float);

    init_acc<<<dim3((N_ROWS * 3 + 255) / 256), 256, 0, stream>>>(sumexp, N_ROWS * 3);
    convert_a_fp8<<<dim3(512), 256, 0, stream>>>((const float4*)A, (uint4*)A8,
                                                 N_ROWS * D_DIM / 16);
    transpose_w_fp8<<<dim3(V_DIM / 64, D_DIM / 64), 256, 0, stream>>>(W, Wt8);
    gemm_ce<<<dim3(N_ROWS / 128, V_DIM / 128), 256, 0, stream>>>(A8, Wt8, tg,
                                                                 sumexp, sumlog, tlog);
    finalize<<<1, 256, 0, stream>>>(sumexp, sumlog, tlog, tg, out);
}